// Round 1
// baseline (243.831 us; speedup 1.0000x reference)
//
#include <hip/hip_runtime.h>

#define Bv 32
#define Av 3
#define Gv 52
#define Cv 80
#define Nv 512
#define Mv (Bv*Av*Gv*Gv)   // 259584
#define HSZ 2048           // shared hash slots (power of 2)
#define NBLK 256
#define NTHR 256

__device__ __forceinline__ float clog_(float x) {
    // clip(log(x), -100) — inputs are in (1e-4, 1-1e-4) so clip rarely fires
    return fmaxf(logf(x), -100.0f);
}

__device__ float block_reduce_sum(float v, float* scratch) {
    #pragma unroll
    for (int o = 32; o > 0; o >>= 1) v += __shfl_down(v, o, 64);
    int lane = threadIdx.x & 63;
    int wid  = threadIdx.x >> 6;
    if (lane == 0) scratch[wid] = v;
    __syncthreads();
    float r = 0.f;
    if (threadIdx.x == 0) {
        #pragma unroll
        for (int i = 0; i < NTHR/64; ++i) r += scratch[i];
    }
    __syncthreads();   // scratch reusable afterwards
    return r;          // valid on thread 0 only
}

// acc layout (floats): 0:sum_all_noobj 1:lx 2:ly 3:lw 4:lh 5:conf_obj
//                      6:n_obj 7:cls_corr 8:n_kill 9:conf_noobj_sub 10:cls_base
//                      11:done counter (int)
__global__ __launch_bounds__(NTHR) void yolo_loss_kernel(
    const float* __restrict__ pred_cls,
    const float* __restrict__ center_x,
    const float* __restrict__ center_y,
    const float* __restrict__ width_,
    const float* __restrict__ height_,
    const float* __restrict__ confidence,
    const float* __restrict__ anchors,
    const float* __restrict__ target,
    float* __restrict__ out,
    float* __restrict__ acc)
{
    __shared__ float red_scratch[NTHR/64];

    // ---- bulk: sum of -clip(log(1-conf)) over ALL cells (float4 loads) ----
    float local = 0.f;
    const float4* c4 = (const float4*)confidence;
    const int total4 = Mv / 4;
    for (int i = blockIdx.x * NTHR + threadIdx.x; i < total4; i += gridDim.x * NTHR) {
        float4 v = c4[i];
        local -= clog_(1.f - v.x) + clog_(1.f - v.y) + clog_(1.f - v.z) + clog_(1.f - v.w);
    }
    float bsum = block_reduce_sum(local, red_scratch);
    if (threadIdx.x == 0) atomicAdd(&acc[0], bsum);

    // ---- block 0: target-side sparse work ----
    if (blockIdx.x == 0) {
        __shared__ int hkey[HSZ];
        __shared__ int hval[HSZ];
        __shared__ int s_cell[Nv];
        __shared__ int s_slot[Nv];
        __shared__ unsigned char s_best[Nv];
        __shared__ short s_lab[Nv];
        __shared__ int s_kill[3*Nv];
        __shared__ int s_objlist[Nv];
        __shared__ int s_objcnt;
        __shared__ float s_anc[6];
        __shared__ float s_acc[8];

        const int tid = threadIdx.x;
        for (int i = tid; i < HSZ; i += NTHR) { hkey[i] = 0; hval[i] = 0; }
        if (tid < 6) s_anc[tid] = anchors[tid];
        if (tid < 8) s_acc[tid] = 0.f;
        if (tid == 0) s_objcnt = 0;
        __syncthreads();

        // Phase A: per-target decode, anchor-IoU argmax, obj-cell hash insert (max-n = last-wins)
        for (int n = tid; n < Nv; n += NTHR) {
            const float* t = target + n*6;
            int si  = (int)t[0];
            int lab = (int)t[1];
            float gx = t[2]*Gv, gy = t[3]*Gv, gw = t[4]*Gv, gh = t[5]*Gv;
            int gi = (int)floorf(gx), gj = (int)floorf(gy);
            float iou[3];
            #pragma unroll
            for (int a = 0; a < 3; ++a) {
                float aw = s_anc[2*a], ah = s_anc[2*a+1];
                float inter = fminf(aw, gw) * fminf(ah, gh);
                float uni = aw*ah + 1e-16f + gw*gh - inter;
                iou[a] = inter / uni;
            }
            int best = 0; float bi = iou[0];
            if (iou[1] > bi) { best = 1; bi = iou[1]; }
            if (iou[2] > bi) { best = 2; bi = iou[2]; }
            int cell = ((si*Av + best)*Gv + gj)*Gv + gi;
            s_cell[n] = cell;
            s_best[n] = (unsigned char)best;
            s_lab[n]  = (short)lab;
            #pragma unroll
            for (int a = 0; a < 3; ++a) {
                bool kill = (a == best) || (iou[a] > 0.5f);
                s_kill[3*n + a] = kill ? ((((si*Av + a)*Gv + gj)*Gv + gi) + 1) : 0;
            }
            unsigned key = (unsigned)cell + 1u;
            unsigned slot = (key * 2654435761u) >> 21;
            for (;;) {
                int prev = atomicCAS(&hkey[slot], 0, (int)key);
                if (prev == 0) {
                    int li = atomicAdd(&s_objcnt, 1);
                    s_objlist[li] = cell;
                    atomicMax(&hval[slot], n + 1);
                    break;
                } else if (prev == (int)key) {
                    atomicMax(&hval[slot], n + 1);
                    break;
                }
                slot = (slot + 1) & (HSZ - 1);
            }
            s_slot[n] = (int)slot;
        }
        __syncthreads();

        // Phase B: representatives (max-n per cell) do coord MSE + conf-obj terms
        for (int n = tid; n < Nv; n += NTHR) {
            if (hval[s_slot[n]] == n + 1) {
                const float* t = target + n*6;
                float gx = t[2]*Gv, gy = t[3]*Gv, gw = t[4]*Gv, gh = t[5]*Gv;
                int best = s_best[n];
                int cell = s_cell[n];
                float tx = gx - floorf(gx);
                float ty = gy - floorf(gy);
                float tw = logf(gw / s_anc[2*best]   + 1e-16f);
                float th = logf(gh / s_anc[2*best+1] + 1e-16f);
                float dx = center_x[cell] - tx;
                float dy = center_y[cell] - ty;
                float dw = width_[cell]  - tw;
                float dh = height_[cell] - th;
                atomicAdd(&s_acc[0], dx*dx);
                atomicAdd(&s_acc[1], dy*dy);
                atomicAdd(&s_acc[2], dw*dw);
                atomicAdd(&s_acc[3], dh*dh);
                atomicAdd(&s_acc[4], -clog_(confidence[cell]));
            }
        }
        __syncthreads();

        // Phase C: distinct (cell,label) pairs -> cls BCE correction  bce(p,1)-bce(p,0)
        for (int i = tid; i < HSZ; i += NTHR) hkey[i] = 0;
        __syncthreads();
        for (int n = tid; n < Nv; n += NTHR) {
            int cell = s_cell[n];
            unsigned key = (unsigned)(cell*Cv + (int)s_lab[n]) + 1u;
            unsigned slot = (key * 2654435761u) >> 21;
            for (;;) {
                int prev = atomicCAS(&hkey[slot], 0, (int)key);
                if (prev == 0) {
                    float p = pred_cls[(size_t)cell*Cv + (int)s_lab[n]];
                    atomicAdd(&s_acc[5], -clog_(p) + clog_(1.f - p));
                    break;
                } else if (prev == (int)key) break;
                slot = (slot + 1) & (HSZ - 1);
            }
        }
        __syncthreads();

        // Phase D: distinct killed cells -> count + subtract their noobj-conf term
        for (int i = tid; i < HSZ; i += NTHR) hkey[i] = 0;
        __syncthreads();
        for (int k = tid; k < 3*Nv; k += NTHR) {
            int key = s_kill[k];
            if (key == 0) continue;
            unsigned slot = ((unsigned)key * 2654435761u) >> 21;
            for (;;) {
                int prev = atomicCAS(&hkey[slot], 0, key);
                if (prev == 0) {
                    int cell = key - 1;
                    atomicAdd(&s_acc[6], 1.0f);
                    atomicAdd(&s_acc[7], -clog_(1.f - confidence[cell]));
                    break;
                } else if (prev == key) break;
                slot = (slot + 1) & (HSZ - 1);
            }
        }
        __syncthreads();

        // Phase E: cls base term  sum over obj cells, all 80 classes of -clip(log(1-p))
        int R = s_objcnt;
        float cb = 0.f;
        for (int k = tid; k < R*Cv; k += NTHR) {
            int ci = k / Cv;
            int c  = k - ci*Cv;
            int cell = s_objlist[ci];
            float p = pred_cls[(size_t)cell*Cv + c];
            cb -= clog_(1.f - p);
        }
        float cbsum = block_reduce_sum(cb, red_scratch);
        if (tid == 0) {
            atomicAdd(&acc[1],  s_acc[0]);
            atomicAdd(&acc[2],  s_acc[1]);
            atomicAdd(&acc[3],  s_acc[2]);
            atomicAdd(&acc[4],  s_acc[3]);
            atomicAdd(&acc[5],  s_acc[4]);
            atomicAdd(&acc[6],  (float)s_objcnt);
            atomicAdd(&acc[7],  s_acc[5]);
            atomicAdd(&acc[8],  s_acc[6]);
            atomicAdd(&acc[9],  s_acc[7]);
            atomicAdd(&acc[10], cbsum);
        }
    }

    // ---- finalize: last block to retire combines everything ----
    if (threadIdx.x == 0) {
        __threadfence();
        int old = atomicAdd((int*)&acc[11], 1);
        if (old == (int)gridDim.x - 1) {
            float sum_all   = atomicAdd(&acc[0], 0.f);
            float lx        = atomicAdd(&acc[1], 0.f);
            float ly        = atomicAdd(&acc[2], 0.f);
            float lw        = atomicAdd(&acc[3], 0.f);
            float lh        = atomicAdd(&acc[4], 0.f);
            float conf_obj  = atomicAdd(&acc[5], 0.f);
            float n_obj     = atomicAdd(&acc[6], 0.f);
            float cls_corr  = atomicAdd(&acc[7], 0.f);
            float n_kill    = atomicAdd(&acc[8], 0.f);
            float conf_sub  = atomicAdd(&acc[9], 0.f);
            float cls_base  = atomicAdd(&acc[10], 0.f);

            float inv_obj = 1.f / n_obj;
            float n_noobj = (float)Mv - n_kill;
            float loss_coord = (lx + ly + lw + lh) * inv_obj;
            float loss_conf  = conf_obj * inv_obj + 100.f * (sum_all - conf_sub) / n_noobj;
            float loss_cls   = (cls_base + cls_corr) * inv_obj / (float)Cv;
            out[0] = loss_coord + loss_conf + loss_cls;
        }
    }
}

extern "C" void kernel_launch(void* const* d_in, const int* in_sizes, int n_in,
                              void* d_out, int out_size, void* d_ws, size_t ws_size,
                              hipStream_t stream) {
    // setup_inputs order: 0:pred_boxes(unused) 1:pred_cls 2:center_x 3:center_y
    //                     4:width 5:height 6:confidence 7:anchors 8:target
    const float* pred_cls   = (const float*)d_in[1];
    const float* center_x   = (const float*)d_in[2];
    const float* center_y   = (const float*)d_in[3];
    const float* width_     = (const float*)d_in[4];
    const float* height_    = (const float*)d_in[5];
    const float* confidence = (const float*)d_in[6];
    const float* anchors    = (const float*)d_in[7];
    const float* target     = (const float*)d_in[8];
    float* acc = (float*)d_ws;

    hipMemsetAsync(acc, 0, 16 * sizeof(float), stream);
    yolo_loss_kernel<<<NBLK, NTHR, 0, stream>>>(
        pred_cls, center_x, center_y, width_, height_, confidence,
        anchors, target, (float*)d_out, acc);
}

// Round 2
// 148.949 us; speedup vs baseline: 1.6370x; 1.6370x over previous
//
#include <hip/hip_runtime.h>

#define Bv 32
#define Av 3
#define Gv 52
#define Cv 80
#define Nv 512
#define Mv (Bv*Av*Gv*Gv)   // 259584
#define HSZ 2048           // shared hash slots (power of 2)
#define NBLK 256
#define NTHR 256

__device__ __forceinline__ float clog_(float x) {
    // clip(log(x), -100)
    return fmaxf(logf(x), -100.0f);
}

__device__ __forceinline__ float wred(float v) {
    #pragma unroll
    for (int o = 32; o > 0; o >>= 1) v += __shfl_down(v, o, 64);
    return v;   // valid on lane 0
}

// acc layout (floats): 0:sum_all_noobj 1:lx 2:ly 3:lw 4:lh 5:conf_obj
//                      6:(unused) 7:cls_corr 8:(unused) 9:conf_noobj_sub 10:cls_base
//                      11:done counter (int) 12:R 13:P 14:K (ints)
//
// ws layout (bytes): [0,64) acc | [64,2112) obj_cell[512] | [2112,10304) obj_t[512] float4
//                    [10304,12352) pair_list[512] | [12352,18496) kill_list[1536]

// ---------- kernel 1: target decode + dedupe (1 block, 512 threads) ----------
__global__ __launch_bounds__(Nv) void targets_kernel(
    const float* __restrict__ anchors,
    const float* __restrict__ target,
    float* __restrict__ acc,
    int* __restrict__ obj_cell,
    float4* __restrict__ obj_t,
    int* __restrict__ pair_list,
    int* __restrict__ kill_list)
{
    __shared__ int hkey[HSZ];
    __shared__ int hval[HSZ];
    __shared__ int ctr[4];
    __shared__ float s_anc[6];

    const int n = threadIdx.x;   // one target per thread (Nv == blockDim)
    for (int i = n; i < HSZ; i += Nv) { hkey[i] = 0; hval[i] = 0; }
    if (n < 6) s_anc[n] = anchors[n];
    if (n < 4) ctr[n] = 0;
    __syncthreads();

    // decode
    const float* t = target + n * 6;
    float gx = t[2] * Gv, gy = t[3] * Gv, gw = t[4] * Gv, gh = t[5] * Gv;
    int si  = (int)t[0];
    int lab = (int)t[1];
    int gi = (int)floorf(gx), gj = (int)floorf(gy);

    float iou[3];
    #pragma unroll
    for (int a = 0; a < 3; ++a) {
        float aw = s_anc[2*a], ah = s_anc[2*a+1];
        float inter = fminf(aw, gw) * fminf(ah, gh);
        float uni = aw*ah + 1e-16f + gw*gh - inter;
        iou[a] = inter / uni;
    }
    int best = 0; float bi = iou[0];
    if (iou[1] > bi) { best = 1; bi = iou[1]; }
    if (iou[2] > bi) { best = 2; bi = iou[2]; }
    int cell = ((si*Av + best)*Gv + gj)*Gv + gi;

    int killk[3];
    #pragma unroll
    for (int a = 0; a < 3; ++a) {
        bool kill = (a == best) || (iou[a] > 0.5f);
        killk[a] = kill ? ((((si*Av + a)*Gv + gj)*Gv + gi) + 1) : 0;
    }

    // obj-cell hash insert; representative = max n (last write wins)
    unsigned key = (unsigned)cell + 1u;
    unsigned slot = (key * 2654435761u) >> 21;
    for (;;) {
        int prev = atomicCAS(&hkey[slot], 0, (int)key);
        if (prev == 0 || prev == (int)key) { atomicMax(&hval[slot], n + 1); break; }
        slot = (slot + 1) & (HSZ - 1);
    }
    __syncthreads();

    // representatives: emit obj cell + coord targets
    if (hval[slot] == n + 1) {
        float tx = gx - floorf(gx);
        float ty = gy - floorf(gy);
        float tw = logf(gw / s_anc[2*best]   + 1e-16f);
        float th = logf(gh / s_anc[2*best+1] + 1e-16f);
        int i = atomicAdd(&ctr[0], 1);
        obj_cell[i] = cell;
        obj_t[i] = make_float4(tx, ty, tw, th);
    }
    __syncthreads();

    // distinct (cell,label) pairs
    for (int i = n; i < HSZ; i += Nv) hkey[i] = 0;
    __syncthreads();
    {
        int pk = cell * Cv + lab;
        unsigned k2 = (unsigned)pk + 1u;
        unsigned s2 = (k2 * 2654435761u) >> 21;
        for (;;) {
            int prev = atomicCAS(&hkey[s2], 0, (int)k2);
            if (prev == 0) { pair_list[atomicAdd(&ctr[1], 1)] = pk; break; }
            if (prev == (int)k2) break;
            s2 = (s2 + 1) & (HSZ - 1);
        }
    }
    __syncthreads();

    // distinct killed cells
    for (int i = n; i < HSZ; i += Nv) hkey[i] = 0;
    __syncthreads();
    #pragma unroll
    for (int a = 0; a < 3; ++a) {
        int k3 = killk[a];
        if (k3 == 0) continue;
        unsigned s3 = ((unsigned)k3 * 2654435761u) >> 21;
        for (;;) {
            int prev = atomicCAS(&hkey[s3], 0, k3);
            if (prev == 0) { kill_list[atomicAdd(&ctr[2], 1)] = k3 - 1; break; }
            if (prev == k3) break;
            s3 = (s3 + 1) & (HSZ - 1);
        }
    }
    __syncthreads();

    if (n < 12) acc[n] = 0.f;            // sums + done counter
    if (n == 0) {
        int* iacc = (int*)acc;
        iacc[12] = ctr[0];   // R = n_obj
        iacc[13] = ctr[1];   // P
        iacc[14] = ctr[2];   // K = n_kill
    }
}

// ---------- kernel 2: bulk sum + parallel scattered terms + finalize ----------
__global__ __launch_bounds__(NTHR) void main_kernel(
    const float* __restrict__ pred_cls,
    const float* __restrict__ center_x,
    const float* __restrict__ center_y,
    const float* __restrict__ width_,
    const float* __restrict__ height_,
    const float* __restrict__ confidence,
    float* __restrict__ out,
    float* __restrict__ acc,
    const int* __restrict__ obj_cell,
    const float4* __restrict__ obj_t,
    const int* __restrict__ pair_list,
    const int* __restrict__ kill_list)
{
    __shared__ float red_scratch[NTHR/64];
    int* iacc = (int*)acc;

    // bulk: sum of -clip(log(1-conf)) over ALL cells
    float local = 0.f;
    const float4* c4 = (const float4*)confidence;
    const int total4 = Mv / 4;
    for (int i = blockIdx.x * NTHR + threadIdx.x; i < total4; i += gridDim.x * NTHR) {
        float4 v = c4[i];
        local -= clog_(1.f - v.x) + clog_(1.f - v.y) + clog_(1.f - v.z) + clog_(1.f - v.w);
    }
    {
        float w = wred(local);
        int lane = threadIdx.x & 63, wid = threadIdx.x >> 6;
        if (lane == 0) red_scratch[wid] = w;
        __syncthreads();
        if (threadIdx.x == 0) {
            float r = 0.f;
            #pragma unroll
            for (int i = 0; i < NTHR/64; ++i) r += red_scratch[i];
            atomicAdd(&acc[0], r);
        }
    }

    const int R = iacc[12];
    const int P = iacc[13];
    const int K = iacc[14];
    const int t = blockIdx.x * NTHR + threadIdx.x;
    const int lane = t & 63;
    const int wave = t >> 6;

    // obj cells: coord MSE + conf-obj  (≤512 items, one per thread)
    if (wave < ((R + 63) >> 6)) {
        float vx = 0, vy = 0, vw = 0, vh = 0, vc = 0;
        if (t < R) {
            int cell = obj_cell[t];
            float4 tt = obj_t[t];
            float dx = center_x[cell] - tt.x;
            float dy = center_y[cell] - tt.y;
            float dw = width_[cell]  - tt.z;
            float dh = height_[cell] - tt.w;
            vx = dx*dx; vy = dy*dy; vw = dw*dw; vh = dh*dh;
            vc = -clog_(confidence[cell]);
        }
        vx = wred(vx); vy = wred(vy); vw = wred(vw); vh = wred(vh); vc = wred(vc);
        if (lane == 0) {
            atomicAdd(&acc[1], vx); atomicAdd(&acc[2], vy);
            atomicAdd(&acc[3], vw); atomicAdd(&acc[4], vh);
            atomicAdd(&acc[5], vc);
        }
    }

    // distinct (cell,label) pairs: cls correction bce(p,1)-bce(p,0)
    if (wave < ((P + 63) >> 6)) {
        float v = 0.f;
        if (t < P) {
            float p = pred_cls[pair_list[t]];
            v = -clog_(p) + clog_(1.f - p);
        }
        v = wred(v);
        if (lane == 0) atomicAdd(&acc[7], v);
    }

    // distinct killed cells: subtract their noobj-conf contribution
    if (wave < ((K + 63) >> 6)) {
        float v = 0.f;
        if (t < K) v = -clog_(1.f - confidence[kill_list[t]]);
        v = wred(v);
        if (lane == 0) atomicAdd(&acc[9], v);
    }

    // cls base: obj cells × all classes of -clip(log(1-p))  (≤40960 items)
    const int E = R * Cv;
    if (wave < ((E + 63) >> 6)) {
        float v = 0.f;
        if (t < E) {
            int ci = t / Cv;
            int c  = t - ci * Cv;
            v = -clog_(1.f - pred_cls[(size_t)obj_cell[ci] * Cv + c]);
        }
        v = wred(v);
        if (lane == 0) atomicAdd(&acc[10], v);
    }

    // finalize: last block to retire
    __syncthreads();
    if (threadIdx.x == 0) {
        __threadfence();
        int old = atomicAdd(&iacc[11], 1);
        if (old == (int)gridDim.x - 1) {
            float sum_all   = atomicAdd(&acc[0], 0.f);
            float lx        = atomicAdd(&acc[1], 0.f);
            float ly        = atomicAdd(&acc[2], 0.f);
            float lw        = atomicAdd(&acc[3], 0.f);
            float lh        = atomicAdd(&acc[4], 0.f);
            float conf_obj  = atomicAdd(&acc[5], 0.f);
            float cls_corr  = atomicAdd(&acc[7], 0.f);
            float conf_sub  = atomicAdd(&acc[9], 0.f);
            float cls_base  = atomicAdd(&acc[10], 0.f);

            float n_obj   = (float)R;
            float n_noobj = (float)Mv - (float)K;
            float inv_obj = 1.f / n_obj;
            float loss_coord = (lx + ly + lw + lh) * inv_obj;
            float loss_conf  = conf_obj * inv_obj + 100.f * (sum_all - conf_sub) / n_noobj;
            float loss_cls   = (cls_base + cls_corr) * inv_obj / (float)Cv;
            out[0] = loss_coord + loss_conf + loss_cls;
        }
    }
}

extern "C" void kernel_launch(void* const* d_in, const int* in_sizes, int n_in,
                              void* d_out, int out_size, void* d_ws, size_t ws_size,
                              hipStream_t stream) {
    // setup_inputs order: 0:pred_boxes(unused) 1:pred_cls 2:center_x 3:center_y
    //                     4:width 5:height 6:confidence 7:anchors 8:target
    const float* pred_cls   = (const float*)d_in[1];
    const float* center_x   = (const float*)d_in[2];
    const float* center_y   = (const float*)d_in[3];
    const float* width_     = (const float*)d_in[4];
    const float* height_    = (const float*)d_in[5];
    const float* confidence = (const float*)d_in[6];
    const float* anchors    = (const float*)d_in[7];
    const float* target     = (const float*)d_in[8];

    char* ws = (char*)d_ws;
    float*  acc       = (float*)ws;              // 64 B
    int*    obj_cell  = (int*)(ws + 64);         // 2048 B
    float4* obj_t     = (float4*)(ws + 2112);    // 8192 B
    int*    pair_list = (int*)(ws + 10304);      // 2048 B
    int*    kill_list = (int*)(ws + 12352);      // 6144 B

    targets_kernel<<<1, Nv, 0, stream>>>(anchors, target, acc,
                                         obj_cell, obj_t, pair_list, kill_list);
    main_kernel<<<NBLK, NTHR, 0, stream>>>(pred_cls, center_x, center_y, width_,
                                           height_, confidence, (float*)d_out, acc,
                                           obj_cell, obj_t, pair_list, kill_list);
}

// Round 3
// 129.485 us; speedup vs baseline: 1.8831x; 1.1503x over previous
//
#include <hip/hip_runtime.h>

#define Bv 32
#define Av 3
#define Gv 52
#define Cv 80
#define Nv 512
#define Mv (Bv*Av*Gv*Gv)   // 259584
#define NBLK 256
#define NTHR 256

// fast ln with the reference's clip(log, -100)
__device__ __forceinline__ float flog(float x) {
    return fmaxf(__logf(x), -100.0f);
}

__device__ __forceinline__ float wred(float v) {
    #pragma unroll
    for (int o = 32; o > 0; o >>= 1) v += __shfl_down(v, o, 64);
    return v;   // valid on lane 0 of each wave
}

// partials layout per block (stride 16 floats):
// 0:bulk_noobj_sum 1:lx 2:ly 3:lw 4:lh 5:conf_obj 6:cls_corr 7:conf_sub
// 8:cls_base 9:n_obj 10:n_kill

__device__ __forceinline__ void decode_target(
    const float* __restrict__ tp, const float* s_anc,
    int& cell, int& pairkey, int kk[3], int& best_out,
    float& gx, float& gy, float& gw, float& gh)
{
    gx = tp[2] * Gv; gy = tp[3] * Gv; gw = tp[4] * Gv; gh = tp[5] * Gv;
    int si  = (int)tp[0];
    int lab = (int)tp[1];
    int gi = (int)floorf(gx), gj = (int)floorf(gy);
    float iou[3];
    #pragma unroll
    for (int a = 0; a < 3; ++a) {
        float aw = s_anc[2*a], ah = s_anc[2*a+1];
        float inter = fminf(aw, gw) * fminf(ah, gh);
        float uni = aw*ah + 1e-16f + gw*gh - inter;
        iou[a] = inter / uni;
    }
    int best = 0; float bi = iou[0];
    if (iou[1] > bi) { best = 1; bi = iou[1]; }
    if (iou[2] > bi) { best = 2; bi = iou[2]; }
    best_out = best;
    cell = ((si*Av + best)*Gv + gj)*Gv + gi;
    pairkey = cell * Cv + lab;
    #pragma unroll
    for (int a = 0; a < 3; ++a) {
        bool kill = (a == best) || (iou[a] > 0.5f);
        kk[a] = kill ? ((((si*Av + a)*Gv + gj)*Gv + gi) + 1) : 0;
    }
}

__global__ __launch_bounds__(NTHR) void main_kernel(
    const float* __restrict__ pred_cls,
    const float* __restrict__ center_x,
    const float* __restrict__ center_y,
    const float* __restrict__ width_,
    const float* __restrict__ height_,
    const float* __restrict__ confidence,
    const float* __restrict__ anchors,
    const float* __restrict__ target,
    float* __restrict__ partials)
{
    __shared__ int   s_cell[Nv];
    __shared__ int   s_pair[Nv];
    __shared__ int   s_kill[3*Nv];
    __shared__ int   s_flag[12];     // [0,1] rep blocked; [2,3] pair blocked; [4..9] kill blocked (j*3+a)
    __shared__ int   s_repcell[2];
    __shared__ float s_acc[11];
    __shared__ float s_anc[6];

    const int t = threadIdx.x;
    if (t < 6)  s_anc[t]  = anchors[t];
    if (t < 12) s_flag[t] = 0;
    if (t < 11) s_acc[t]  = 0.f;
    __syncthreads();

    // ---- redundant decode of all 512 targets into LDS (2 per thread) ----
    for (int n = t; n < Nv; n += NTHR) {
        int cell, pair, kk[3], best; float gx, gy, gw, gh;
        decode_target(target + n*6, s_anc, cell, pair, kk, best, gx, gy, gw, gh);
        s_cell[n] = cell;
        s_pair[n] = pair;
        s_kill[3*n+0] = kk[0]; s_kill[3*n+1] = kk[1]; s_kill[3*n+2] = kk[2];
    }
    __syncthreads();

    // ---- dedup scan for this block's two owned targets ----
    const int n0 = 2 * blockIdx.x;          // owns n0, n0+1
    const int c0 = s_cell[n0],   c1 = s_cell[n0+1];
    const int p0 = s_pair[n0],   p1 = s_pair[n0+1];
    int k0[3], k1[3];
    #pragma unroll
    for (int a = 0; a < 3; ++a) { k0[a] = s_kill[3*n0+a]; k1[a] = s_kill[3*n0+3+a]; }

    for (int m = t; m < Nv; m += NTHR) {
        int cm = s_cell[m];
        if (m > n0     && cm == c0) s_flag[0] = 1;   // rep = max-n (last .set wins)
        if (m > n0 + 1 && cm == c1) s_flag[1] = 1;
        int pm = s_pair[m];
        if (m < n0     && pm == p0) s_flag[2] = 1;   // pair handled by min-n
        if (m < n0 + 1 && pm == p1) s_flag[3] = 1;
        #pragma unroll
        for (int a = 0; a < 3; ++a) {
            int km = s_kill[3*m + a];
            if (!km) continue;
            int idx = 3*m + a;
            #pragma unroll
            for (int a2 = 0; a2 < 3; ++a2) {
                if (idx < 3*n0 + a2     && km == k0[a2]) s_flag[4 + a2] = 1;
                if (idx < 3*(n0+1) + a2 && km == k1[a2]) s_flag[7 + a2] = 1;
            }
        }
    }
    __syncthreads();

    // ---- owned-target contributions (thread 0 -> n0, thread 64 -> n0+1) ----
    if (t == 0 || t == 64) {
        const int j = t >> 6;
        const int n = n0 + j;
        int cell, pair, kk[3], best; float gx, gy, gw, gh;
        decode_target(target + n*6, s_anc, cell, pair, kk, best, gx, gy, gw, gh);

        int repv = 0;
        if (!s_flag[j]) {                       // I'm this cell's representative
            float tx = gx - floorf(gx);
            float ty = gy - floorf(gy);
            float tw = __logf(gw / s_anc[2*best]   + 1e-16f);
            float th = __logf(gh / s_anc[2*best+1] + 1e-16f);
            float dx = center_x[cell] - tx;
            float dy = center_y[cell] - ty;
            float dw = width_[cell]  - tw;
            float dh = height_[cell] - th;
            atomicAdd(&s_acc[1], dx*dx);
            atomicAdd(&s_acc[2], dy*dy);
            atomicAdd(&s_acc[3], dw*dw);
            atomicAdd(&s_acc[4], dh*dh);
            atomicAdd(&s_acc[5], -flog(confidence[cell]));
            atomicAdd(&s_acc[9], 1.f);          // n_obj
            repv = 1;
        }
        s_repcell[j] = repv ? cell : -1;

        if (!s_flag[2 + j]) {                   // first occurrence of (cell,label)
            float p = pred_cls[(size_t)pair];
            atomicAdd(&s_acc[6], -flog(p) + flog(1.f - p));
        }

        float csub = 0.f, nk = 0.f;
        #pragma unroll
        for (int a = 0; a < 3; ++a) {
            int kc = kk[a];
            if (kc && !s_flag[4 + 3*j + a]) {   // first occurrence of killed cell
                csub += -flog(1.f - confidence[kc - 1]);
                nk += 1.f;
            }
        }
        if (nk != 0.f) { atomicAdd(&s_acc[7], csub); atomicAdd(&s_acc[10], nk); }
    }
    __syncthreads();

    // ---- cls base for owned representative cells (80 classes each) ----
    {
        const int j = t >> 7;                   // threads 0-127 -> rep0, 128-255 -> rep1
        const int c = t & 127;
        float v = 0.f;
        int cell = s_repcell[j];
        if (cell >= 0 && c < Cv)
            v = -flog(1.f - pred_cls[(size_t)cell * Cv + c]);
        v = wred(v);
        if ((t & 63) == 0) atomicAdd(&s_acc[8], v);
    }

    // ---- bulk: sum of -clip(log(1-conf)) over ALL cells ----
    {
        float local = 0.f;
        const float4* c4 = (const float4*)confidence;
        for (int i = blockIdx.x * NTHR + t; i < Mv/4; i += NBLK * NTHR) {
            float4 v = c4[i];
            local -= flog(1.f - v.x) + flog(1.f - v.y) + flog(1.f - v.z) + flog(1.f - v.w);
        }
        local = wred(local);
        if ((t & 63) == 0) atomicAdd(&s_acc[0], local);
    }
    __syncthreads();

    // ---- plain-store this block's partials (no init of ws required) ----
    if (t < 11) partials[blockIdx.x * 16 + t] = s_acc[t];
}

__global__ __launch_bounds__(NBLK) void reduce_kernel(
    const float* __restrict__ partials, float* __restrict__ out)
{
    __shared__ float s_r[4][11];
    const int t = threadIdx.x;           // one thread per block-slot
    float v[11];
    #pragma unroll
    for (int j = 0; j < 11; ++j) v[j] = partials[t * 16 + j];
    #pragma unroll
    for (int j = 0; j < 11; ++j) v[j] = wred(v[j]);
    const int lane = t & 63, w = t >> 6;
    if (lane == 0) {
        #pragma unroll
        for (int j = 0; j < 11; ++j) s_r[w][j] = v[j];
    }
    __syncthreads();
    if (t == 0) {
        float a[11];
        #pragma unroll
        for (int j = 0; j < 11; ++j)
            a[j] = s_r[0][j] + s_r[1][j] + s_r[2][j] + s_r[3][j];
        float n_obj   = a[9];
        float n_kill  = a[10];
        float inv_obj = 1.f / n_obj;
        float n_noobj = (float)Mv - n_kill;
        float loss_coord = (a[1] + a[2] + a[3] + a[4]) * inv_obj;
        float loss_conf  = a[5] * inv_obj + 100.f * (a[0] - a[7]) / n_noobj;
        float loss_cls   = (a[8] + a[6]) * inv_obj / (float)Cv;
        out[0] = loss_coord + loss_conf + loss_cls;
    }
}

extern "C" void kernel_launch(void* const* d_in, const int* in_sizes, int n_in,
                              void* d_out, int out_size, void* d_ws, size_t ws_size,
                              hipStream_t stream) {
    // setup_inputs order: 0:pred_boxes(unused) 1:pred_cls 2:center_x 3:center_y
    //                     4:width 5:height 6:confidence 7:anchors 8:target
    const float* pred_cls   = (const float*)d_in[1];
    const float* center_x   = (const float*)d_in[2];
    const float* center_y   = (const float*)d_in[3];
    const float* width_     = (const float*)d_in[4];
    const float* height_    = (const float*)d_in[5];
    const float* confidence = (const float*)d_in[6];
    const float* anchors    = (const float*)d_in[7];
    const float* target     = (const float*)d_in[8];
    float* partials = (float*)d_ws;   // 256 blocks × 16 floats = 16 KB

    main_kernel<<<NBLK, NTHR, 0, stream>>>(pred_cls, center_x, center_y, width_,
                                           height_, confidence, anchors, target,
                                           partials);
    reduce_kernel<<<1, NBLK, 0, stream>>>(partials, (float*)d_out);
}